// Round 10
// baseline (306.609 us; speedup 1.0000x reference)
//
#include <hip/hip_runtime.h>
#include <cstdint>
#include <cstddef>

typedef unsigned short u16;
typedef __attribute__((ext_vector_type(8))) short sh8;       // 8 x 16-bit (4 VGPR)
typedef __attribute__((ext_vector_type(8))) _Float16 hf8;    // 8 fp16 (4 VGPR)
typedef __attribute__((ext_vector_type(4))) float f4;        // 4 f32

#define MFMA16B(a, b, c) __builtin_amdgcn_mfma_f32_16x16x32_bf16((a), (b), (c), 0, 0, 0)
#define MFMA16H(a, b, c) __builtin_amdgcn_mfma_f32_16x16x32_f16((a), (b), (c), 0, 0, 0)

__device__ __forceinline__ u16 f2bf(float f) {
  union { float f; uint32_t u; } v; v.f = f;
  uint32_t u = v.u;
  uint32_t lsb = (u >> 16) & 1u;
  return (u16)((u + 0x7fffu + lsb) >> 16);   // RNE
}
__device__ __forceinline__ float bf2f(u16 h) {
  union { uint32_t u; float f; } v; v.u = ((uint32_t)h) << 16;
  return v.f;
}

// async global->LDS, 16B per lane. LDS dest must be linear in lane order.
__device__ __forceinline__ void aload16(const void* g, void* l) {
  __builtin_amdgcn_global_load_lds(
      (const __attribute__((address_space(1))) uint32_t*)g,
      (__attribute__((address_space(3))) uint32_t*)l, 16, 0, 0);
}

// ---------------------------------------------------------------------------
// Kernel 1: split fp32 weights into 2 fp16 planes.
// qkv layout: [1536][1024] rows = (q|k|v), cols 0-511 = h0, 512-1023 = h1.
// proj layout: [sp][512][512] (for R6-style proj kernel).
// ---------------------------------------------------------------------------
__global__ void prep_weights(const float* __restrict__ qw, const float* __restrict__ kw,
                             const float* __restrict__ vw, const float* __restrict__ pw,
                             u16* __restrict__ w2qkv, u16* __restrict__ w2p) {
  #pragma clang fp contract(off)
  int row = blockIdx.x;  // 0..2047
  for (int c = threadIdx.x; c < 512; c += 256) {
    const float* src;
    if (row < 1536) {
      int br = row >> 9;
      src = (br == 0 ? qw : (br == 1 ? kw : vw)) + (size_t)(row & 511) * 512;
    } else {
      src = pw + (size_t)(row - 1536) * 512;
    }
    float w = src[c];
    _Float16 h0 = (_Float16)w;
    float r1 = w - (float)h0;
    _Float16 h1 = (_Float16)r1;
    union { _Float16 h; u16 u; } u0, u1;
    u0.h = h0; u1.h = h1;
    if (row < 1536) {
      w2qkv[(size_t)row * 1024 + c] = u0.u;
      w2qkv[(size_t)row * 1024 + 512 + c] = u1.u;
    } else {
      int m = row - 1536;
      w2p[(size_t)m * 512 + c] = u0.u;
      w2p[(size_t)(512 + m) * 512 + c] = u1.u;
    }
  }
}

// single launch: grid(8) = 4 sets x 2 halves
__global__ void bn_prep(const float* __restrict__ g0, const float* __restrict__ b0,
                        const float* __restrict__ m0, const float* __restrict__ v0,
                        const float* __restrict__ g1, const float* __restrict__ b1,
                        const float* __restrict__ m1, const float* __restrict__ v1,
                        const float* __restrict__ g2, const float* __restrict__ b2,
                        const float* __restrict__ m2, const float* __restrict__ v2,
                        const float* __restrict__ g3, const float* __restrict__ b3,
                        const float* __restrict__ m3, const float* __restrict__ v3,
                        float* __restrict__ inv, float* __restrict__ add) {
  #pragma clang fp contract(off)
  int s = blockIdx.x >> 1;
  int i = (blockIdx.x & 1) * 256 + threadIdx.x;
  const float* g  = s == 0 ? g0 : s == 1 ? g1 : s == 2 ? g2 : g3;
  const float* be = s == 0 ? b0 : s == 1 ? b1 : s == 2 ? b2 : b3;
  const float* mu = s == 0 ? m0 : s == 1 ? m1 : s == 2 ? m2 : m3;
  const float* va = s == 0 ? v0 : s == 1 ? v1 : s == 2 ? v2 : v3;
  float iv = g[i] / sqrtf(va[i] + 1e-5f);
  inv[s * 512 + i] = iv;
  add[s * 512 + i] = be[i] - mu[i] * iv;
}

// ---------------------------------------------------------------------------
// Kernel 2: LIF over x -> spikes, stored TRANSPOSED sT[t][b][n][c] (fp16: 0x3C00).
// ---------------------------------------------------------------------------
__global__ __launch_bounds__(256) void lif0(const float* __restrict__ x, u16* __restrict__ sT) {
  #pragma clang fp contract(off)
  __shared__ u16 st[64 * 80];   // [n][c] padded
  const int tid = threadIdx.x;
  const int n0 = blockIdx.x * 64;
  const int c0 = blockIdx.y * 64;
  const int b = blockIdx.z;
  const int cl = tid >> 2;
  const int ns = (tid & 3) * 16;
  const int nr = tid >> 2;
  const int cs = (tid & 3) * 16;
  float vv[16];
#pragma unroll
  for (int i = 0; i < 16; i++) vv[i] = 0.f;
  for (int t = 0; t < 4; ++t) {
    const float* xp = x + ((size_t)((t * 8 + b) * 512 + c0 + cl)) * 1024 + n0 + ns;
#pragma unroll
    for (int q = 0; q < 4; ++q) {
      f4 xv = *(const f4*)(xp + q * 4);
#pragma unroll
      for (int j = 0; j < 4; ++j) {
        int i = q * 4 + j;
        float v2 = vv[i] + (xv[j] - vv[i]) * 0.5f;   // v + (x-v)/tau
        int spk = (v2 - 1.0f >= 0.0f);
        st[(ns + i) * 80 + cl] = spk ? (u16)0x3C00 : (u16)0;   // fp16 one
        vv[i] = spk ? 0.0f : v2;
      }
    }
    __syncthreads();
    u16* gp = sT + ((size_t)((t * 8 + b) * 1024 + n0 + nr)) * 512 + c0 + cs;
    *(sh8*)(gp) = *(const sh8*)&st[nr * 80 + cs];
    *(sh8*)(gp + 8) = *(const sh8*)&st[nr * 80 + cs + 8];
    __syncthreads();
  }
}

// ---------------------------------------------------------------------------
// Kernel 3: stacked QKV GEMM + BN + LIF. R10: cross-boundary frag prefetch.
// BM=96 BN=256, 512 thr (2Mx4N waves, wave 48x64). Reg-dbuf fragments:
// per tile i: issue stages(i+2) -> ds_read frags(i+1) into OTHER reg set ->
// MFMA(i) on current set -> counted drain -> one barrier. LDS-read port
// overlaps MFMA within each wave. A dbuf 2x12KB, B tri-buf 3x32KB (R6's
// verified conflict-free pair scheme). Grid 512 = 2 balanced rounds.
// Per-acc MFMA k-order identical to R6 -> bit-identical numerics.
// ---------------------------------------------------------------------------
__global__ __launch_bounds__(512, 2) void qkv_gemm(
    const u16* __restrict__ w2,      // [1536][1024]  (h0 | h1)
    const u16* __restrict__ sT,      // [t][b][n][512]
    const float* __restrict__ inv4, const float* __restrict__ add4,
    u16* __restrict__ qs, u16* __restrict__ ks, u16* __restrict__ vs) {
  #pragma clang fp contract(off)
  __shared__ u16 lA[2][96 * 64];    // 2 x 12KB : [row][pl*32 + k]
  __shared__ u16 lB[3][256 * 64];   // 3 x 32KB : [row][sub*32 + k]
  const int tid = threadIdx.x;
  const int bid = blockIdx.x;               // 512 blocks
  const int orig = (bid & 7) * 64 + (bid >> 3);   // XCD-chunked (512%8==0)
  const int mI = orig & 15;
  const int nI = (orig >> 4) & 3;
  const int b  = orig >> 6;
  const int m0 = mI * 96;
  const int n0 = nI * 256;
  const int wid = tid >> 6, lane = tid & 63;
  const int l15 = lane & 15, l4 = lane >> 4;
  const int wm = wid >> 2, wn = wid & 3;    // 2M x 4N, wave tile 48x64
  const int swz = l15 & 7;                  // read-side XOR
  // staging: thread -> (row = tid>>3, phys slot = tid&7); logical = phys^(row&7)
  const int ss = (tid & 7) ^ ((tid >> 3) & 7);
  const int aoff1 = (m0 + (tid >> 3)) * 1024 + (ss >> 2) * 512 + (ss & 3) * 8;
  const int aoff2 = aoff1 + 64 * 1024;      // rows 64..95 (threads < 256)
  int boff[4];
#pragma unroll
  for (int c = 0; c < 4; ++c)
    boff[c] = (n0 + c * 64 + (tid >> 3)) * 512 + (ss >> 2) * 32 + (ss & 3) * 8;

  auto stA = [&](int j) {                    // A window j -> lA[j&1]
    int k0 = (j & 15) * 32;
    u16* d = &lA[j & 1][0];
    aload16(w2 + (size_t)(aoff1 + k0), d + tid * 8);
    if (tid < 256) aload16(w2 + (size_t)(aoff2 + k0), d + 4096 + tid * 8);
  };
  auto stB = [&](int P) {                    // pair P -> lB[P%3]
    int k0 = (P & 7) * 64;
    const u16* bb = sT + (size_t)(P >> 3) * 4194304 + (size_t)b * 524288;
    u16* d = &lB[P % 3][0];
#pragma unroll
    for (int c = 0; c < 4; ++c)
      aload16(bb + (size_t)(boff[c] + k0), d + c * 4096 + tid * 8);
  };

  const f4 fz = {0.f, 0.f, 0.f, 0.f};
  f4 acc[3][4];
  f4 vst[3][4];
#pragma unroll
  for (int i = 0; i < 3; i++)
#pragma unroll
    for (int j = 0; j < 4; j++) vst[i][j] = fz;

  // two named fragment sets (rule #20: no runtime-indexed reg arrays)
  hf8 Ae0[3], Ae1[3], Be[4];
  hf8 Ao0[3], Ao1[3], Bo[4];

#define READF(A0_, A1_, B_, jj)                                               \
  {                                                                           \
    const u16* bA = &lA[(jj) & 1][0];                                         \
    const u16* bB = &lB[((jj) >> 1) % 3][0];                                  \
    const int sb_ = ((jj) & 1) * 4;                                           \
    _Pragma("unroll") for (int mf = 0; mf < 3; ++mf) {                        \
      int r_ = wm * 48 + mf * 16 + l15;                                       \
      A0_[mf] = *(const hf8*)&bA[r_ * 64 + ((l4 ^ swz) * 8)];                 \
      A1_[mf] = *(const hf8*)&bA[r_ * 64 + (((4 + l4) ^ swz) * 8)];           \
    }                                                                         \
    _Pragma("unroll") for (int nf = 0; nf < 4; ++nf) {                        \
      int r_ = wn * 64 + nf * 16 + l15;                                       \
      B_[nf] = *(const hf8*)&bB[r_ * 64 + (((sb_ + l4) ^ swz) * 8)];          \
    }                                                                         \
  }

#define TILE_MFMA(A0_, A1_, B_)                                               \
  {                                                                           \
    __builtin_amdgcn_s_setprio(1);                                            \
    _Pragma("unroll") for (int nf = 0; nf < 4; ++nf)                          \
      _Pragma("unroll") for (int mf = 0; mf < 3; ++mf)                        \
        acc[mf][nf] = MFMA16H(A0_[mf], B_[nf], acc[mf][nf]);                  \
    _Pragma("unroll") for (int nf = 0; nf < 4; ++nf)                          \
      _Pragma("unroll") for (int mf = 0; mf < 3; ++mf)                        \
        acc[mf][nf] = MFMA16H(A1_[mf], B_[nf], acc[mf][nf]);                  \
    __builtin_amdgcn_s_setprio(0);                                            \
  }

  // prologue: A(0),A(1),B(pair0),B(pair1); publish A0,A1,B0; keep B1 in flight
  stA(0); stA(1); stB(0); stB(1);
  asm volatile("s_waitcnt vmcnt(4)" ::: "memory");
  __builtin_amdgcn_s_barrier();
  __builtin_amdgcn_sched_barrier(0);
  READF(Ae0, Ae1, Be, 0);                    // frags(0) -> even set

  for (int t = 0; t < 4; ++t) {
#pragma unroll
    for (int i = 0; i < 3; i++)
#pragma unroll
      for (int j = 0; j < 4; j++) acc[i][j] = fz;

    for (int p = 0; p < 8; ++p) {
      const int ii = t * 16 + p * 2;
      const int P = ii >> 1;                 // = t*8 + p
      // ===== EVEN tile ii: compute even set, prefetch odd set =====
      stA(ii + 2);
      const bool issueB = (P + 2 < 32);
      if (issueB) stB(P + 2);
      READF(Ao0, Ao1, Bo, ii + 1);           // frags(ii+1), overlaps MFMAs
      TILE_MFMA(Ae0, Ae1, Be);
      if (issueB) {
        asm volatile("s_waitcnt vmcnt(4)" ::: "memory");   // keep B(P+2)
      } else {
        asm volatile("s_waitcnt vmcnt(0)" ::: "memory");
      }
      __builtin_amdgcn_s_barrier();
      __builtin_amdgcn_sched_barrier(0);
      // ===== ODD tile ii+1: compute odd set, prefetch even set =====
      stA(ii + 3);
      READF(Ae0, Ae1, Be, ii + 2);           // frags(ii+2)
      TILE_MFMA(Ao0, Ao1, Bo);
      asm volatile("s_waitcnt vmcnt(0)" ::: "memory");
      __builtin_amdgcn_s_barrier();
      __builtin_amdgcn_sched_barrier(0);
    }
    // epilogue: BN + LIF + spike store (bf16 spikes)
#pragma unroll
    for (int mf = 0; mf < 3; ++mf) {
      int f0 = m0 + wm * 48 + mf * 16;       // 16-aligned; never straddles 512
      int br = f0 >> 9;
      u16* dst = br == 0 ? qs : (br == 1 ? ks : vs);
      int ocb = f0 & 511;
#pragma unroll
      for (int r = 0; r < 4; ++r) {
        int oc = ocb + l4 * 4 + r;
        float iv = inv4[br * 512 + oc];
        float ad = add4[br * 512 + oc];
        size_t rowbase = ((size_t)((t * 8 + b) * 512 + oc)) * 1024 + n0;
#pragma unroll
        for (int nf = 0; nf < 4; ++nf) {
          float z = acc[mf][nf][r] * iv + ad;
          float v2 = vst[mf][nf][r];
          v2 = v2 + (z - v2) * 0.5f;
          int spk = (v2 - 1.0f >= 0.0f);
          vst[mf][nf][r] = spk ? 0.0f : v2;
          dst[rowbase + wn * 64 + nf * 16 + l15] = spk ? (u16)0x3F80 : (u16)0;
        }
      }
    }
  }
#undef READF
#undef TILE_MFMA
}

// ---------------------------------------------------------------------------
// Kernel 4: kvT[e][d] = sum_n v[e,n]*k[d,n], per (t,b,h), single pass K=1024.
// ---------------------------------------------------------------------------
__global__ __launch_bounds__(256) void kv_gemm(const u16* __restrict__ ks,
                                               const u16* __restrict__ vs,
                                               float* __restrict__ kvp) {
  const int tbh = blockIdx.x;  // (t*8+b)*8+h ; 256 blocks
  const int tid = threadIdx.x;
  const int wv = tid >> 6, lane = tid & 63, l15 = lane & 15, l4 = lane >> 4;
  const size_t cb = ((size_t)(tbh >> 3) * 512 + (size_t)(tbh & 7) * 64) * 1024;
  const u16* vbase = vs + cb;
  const u16* kbase = ks + cb;
  const f4 fz = {0.f, 0.f, 0.f, 0.f};
  f4 acc[4];
#pragma unroll
  for (int i = 0; i < 4; i++) acc[i] = fz;
  for (int s = 0; s < 32; ++s) {
    int kk = s * 32 + l4 * 8;
    sh8 av = *(const sh8*)(vbase + (size_t)(wv * 16 + l15) * 1024 + kk);
#pragma unroll
    for (int df = 0; df < 4; ++df) {
      sh8 bk = *(const sh8*)(kbase + (size_t)(df * 16 + l15) * 1024 + kk);
      acc[df] = MFMA16B(av, bk, acc[df]);
    }
  }
  float* out = kvp + (size_t)tbh * 4096;
#pragma unroll
  for (int df = 0; df < 4; ++df)
#pragma unroll
    for (int r = 0; r < 4; ++r)
      out[(wv * 16 + l4 * 4 + r) * 64 + df * 16 + l15] = acc[df][r];
}

// ---------------------------------------------------------------------------
// Kernel 5: att = (kv^T @ q)*0.125 per head, then LIF; exact integer path.
// ---------------------------------------------------------------------------
__global__ __launch_bounds__(256) void att_lif(const u16* __restrict__ qs,
                                               const float* __restrict__ kvp,
                                               u16* __restrict__ aT) {
  #pragma clang fp contract(off)
  __shared__ u16 ldsb[64 * 72 * 2 + 128 * 72];
  u16* lkhi = ldsb;                 // [64 e][72]
  u16* lklo = ldsb + 64 * 72;       // [64 e][72]
  u16* lqT = ldsb + 64 * 72 * 2;    // [128 n][72]
  u16* lsp = ldsb;                  // alias: [128 n][72] spike transpose buf
  const int tid = threadIdx.x;
  const int n0 = blockIdx.x * 128;
  const int b = blockIdx.y >> 3;
  const int h = blockIdx.y & 7;
  const int wv = tid >> 6, lane = tid & 63, l15 = lane & 15, l4 = lane >> 4;
  const int e_s = tid >> 2, ds_ = (tid & 3) * 16;
  const f4 fz = {0.f, 0.f, 0.f, 0.f};
  f4 vst[4][2];
#pragma unroll
  for (int i = 0; i < 4; i++)
#pragma unroll
    for (int j = 0; j < 2; j++) vst[i][j] = fz;

  for (int t = 0; t < 4; ++t) {
    int tb = t * 8 + b;
    int tbh = tb * 8 + h;
    {  // stage kv: split into exact bf16 hi/lo
      const float* base = kvp + (size_t)tbh * 4096 + e_s * 64 + ds_;
#pragma unroll
      for (int q = 0; q < 4; ++q) {
        f4 s4 = *(const f4*)(base + q * 4);
#pragma unroll
        for (int j = 0; j < 4; ++j) {
          float sv = s4[j];
          u16 hb = f2bf(sv);
          float lof = sv - bf2f(hb);
          lkhi[e_s * 72 + ds_ + q * 4 + j] = hb;
          lklo[e_s * 72 + ds_ + q * 4 + j] = f2bf(lof);
        }
      }
    }
    {  // stage q transposed: lqT[n][d]
      const u16* qb = qs + ((size_t)tb * 512 + h * 64) * 1024 + n0;
#pragma unroll
      for (int it = 0; it < 4; ++it) {
        int lin = it * 2048 + tid * 8;
        int d = lin >> 7, j0 = lin & 127;
        sh8 qv = *(const sh8*)(qb + (size_t)d * 1024 + j0);
#pragma unroll
        for (int j = 0; j < 8; ++j) lqT[(j0 + j) * 72 + d] = (u16)qv[j];
      }
    }
    __syncthreads();
    f4 acc[4][2];
#pragma unroll
    for (int i = 0; i < 4; i++)
#pragma unroll
      for (int j = 0; j < 2; j++) acc[i][j] = fz;
#pragma unroll
    for (int ksx = 0; ksx < 2; ++ksx) {
      sh8 bq[2];
#pragma unroll
      for (int nf = 0; nf < 2; ++nf)
        bq[nf] = *(const sh8*)&lqT[(wv * 32 + nf * 16 + l15) * 72 + ksx * 32 + l4 * 8];
#pragma unroll
      for (int mf = 0; mf < 4; ++mf) {
        sh8 ah = *(const sh8*)&lkhi[(mf * 16 + l15) * 72 + ksx * 32 + l4 * 8];
        sh8 al = *(const sh8*)&lklo[(mf * 16 + l15) * 72 + ksx * 32 + l4 * 8];
#pragma unroll
        for (int nf = 0; nf < 2; ++nf) {
          acc[mf][nf] = MFMA16B(ah, bq[nf], acc[mf][nf]);
          acc[mf][nf] = MFMA16B(al, bq[nf], acc[mf][nf]);
        }
      }
    }
    __syncthreads();  // all reads of lkhi/lklo done before alias overwrite
#pragma unroll
    for (int mf = 0; mf < 4; ++mf)
#pragma unroll
      for (int nf = 0; nf < 2; ++nf)
#pragma unroll
        for (int r = 0; r < 4; ++r) {
          float xatt = acc[mf][nf][r] * 0.125f;  // exact
          float v2 = vst[mf][nf][r];
          v2 = v2 + (xatt - v2) * 0.5f;          // exact dyadic
          int spk = (v2 - 1.0f >= 0.0f);
          vst[mf][nf][r] = spk ? 0.0f : v2;
          int e = mf * 16 + l4 * 4 + r;
          int n = wv * 32 + nf * 16 + l15;
          lsp[n * 72 + e] = spk ? (u16)0x3C00 : (u16)0;   // fp16 one
        }
    __syncthreads();
    {  // store a_T rows (c contiguous)
#pragma unroll
      for (int it = 0; it < 2; ++it) {
        int lin = it * 256 + tid;
        int n = lin >> 2, es = (lin & 3) * 16;
        u16* gp = aT + ((size_t)(tb * 1024 + n0 + n)) * 512 + h * 64 + es;
        *(sh8*)gp = *(const sh8*)&lsp[n * 72 + es];
        *(sh8*)(gp + 8) = *(const sh8*)&lsp[n * 72 + es + 8];
      }
    }
    __syncthreads();
  }
}

// ---------------------------------------------------------------------------
// Kernel 6: proj GEMM (2-plane fp16) + bias + BN -> out fp32 (R6 structure).
// ---------------------------------------------------------------------------
__global__ __launch_bounds__(256, 2) void proj_gemm(
    const u16* __restrict__ w2, const u16* __restrict__ aT,
    const float* __restrict__ inv4, const float* __restrict__ add4,
    const float* __restrict__ pb, float* __restrict__ out) {
  #pragma clang fp contract(off)
  __shared__ u16 lA[2 * 128 * 32];
  __shared__ u16 lB[128 * 32];
  const int tid = threadIdx.x;
  const int m0 = blockIdx.x * 128;
  const int n0 = blockIdx.y * 128;
  const int tb = blockIdx.z;
  const int lane = tid & 63, wv = tid >> 6;
  const int l15 = lane & 15, l4 = lane >> 4;
  const int wm = wv >> 1, wn = wv & 1;
  const int rA = tid >> 2;
  const int kswz = (((tid & 3) ^ ((tid >> 3) & 3)) * 8);
  const int sA = (l4 ^ ((l15 >> 1) & 3)) * 8;

  size_t aoff[4];
#pragma unroll
  for (int c = 0; c < 4; ++c) {
    int rf = c * 64 + rA;
    int sp = rf >> 7, r = rf & 127;
    aoff[c] = (size_t)(sp * 512 + m0 + r) * 512 + kswz;
  }
  size_t boff[2];
#pragma unroll
  for (int c = 0; c < 2; ++c) boff[c] = (size_t)(c * 64 + rA) * 512 + kswz;

  const f4 fz = {0.f, 0.f, 0.f, 0.f};
  f4 acc[4][4];
#pragma unroll
  for (int i = 0; i < 4; i++)
#pragma unroll
    for (int j = 0; j < 4; j++) acc[i][j] = fz;
  const u16* aTt = aT + ((size_t)tb * 1024 + n0) * 512;

  for (int k0 = 0; k0 < 512; k0 += 32) {
#pragma unroll
    for (int c = 0; c < 4; ++c)
      aload16(w2 + aoff[c] + k0, &lA[c * 2048 + tid * 8]);
#pragma unroll
    for (int c = 0; c < 2; ++c)
      aload16(aTt + boff[c] + k0, &lB[c * 2048 + tid * 8]);
    __syncthreads();
    hf8 bfr[4];
#pragma unroll
    for (int nf = 0; nf < 4; ++nf)
      bfr[nf] = *(const hf8*)&lB[(wn * 64 + nf * 16 + l15) * 32 + sA];
#pragma unroll
    for (int sp = 0; sp < 2; ++sp) {
#pragma unroll
      for (int mf = 0; mf < 4; ++mf) {
        hf8 afr = *(const hf8*)&lA[sp * 4096 + (wm * 64 + mf * 16 + l15) * 32 + sA];
#pragma unroll
        for (int nf = 0; nf < 4; ++nf) acc[mf][nf] = MFMA16H(afr, bfr[nf], acc[mf][nf]);
      }
    }
    __syncthreads();
  }
#pragma unroll
  for (int mf = 0; mf < 4; ++mf) {
#pragma unroll
    for (int r = 0; r < 4; ++r) {
      int o = m0 + wm * 64 + mf * 16 + l4 * 4 + r;
      float iv = inv4[3 * 512 + o];
      float ad = add4[3 * 512 + o];
      float bias = pb[o];
      size_t rowbase = ((size_t)(tb * 512 + o)) * 1024 + n0;
#pragma unroll
      for (int nf = 0; nf < 4; ++nf) {
        float z = (acc[mf][nf][r] + bias) * iv + ad;
        out[rowbase + wn * 64 + nf * 16 + l15] = z;
      }
    }
  }
}

// ---------------------------------------------------------------------------
extern "C" void kernel_launch(void* const* d_in, const int* in_sizes, int n_in,
                              void* d_out, int out_size, void* d_ws, size_t ws_size,
                              hipStream_t stream) {
  const float* x = (const float*)d_in[0];
  const float* qw = (const float*)d_in[1];
  const float* kw = (const float*)d_in[6];
  const float* vw = (const float*)d_in[11];
  const float* pw = (const float*)d_in[16];
  const float* pb = (const float*)d_in[21];

  char* p = (char*)d_ws;
  u16* w2qkv = (u16*)p; p += (size_t)1536 * 1024 * 2;      // 3.1 MB
  u16* w2p = (u16*)p;   p += (size_t)2 * 512 * 512 * 2;    // 1.0 MB
  float* inv4 = (float*)p; p += 4 * 512 * 4;
  float* add4 = (float*)p; p += 4 * 512 * 4;
  u16* sT = (u16*)p;    p += (size_t)4 * 8 * 1024 * 512 * 2;  // 33.5 MB (reused as aT)
  u16* qs = (u16*)p;    p += (size_t)4 * 8 * 512 * 1024 * 2;
  u16* ks = (u16*)p;    p += (size_t)4 * 8 * 512 * 1024 * 2;
  u16* vs = (u16*)p;    p += (size_t)4 * 8 * 512 * 1024 * 2;
  float* kvp = (float*)p; p += (size_t)256 * 4096 * 4;        // 4.2 MB
  u16* aT = sT;  // s_T dead after qkv_gemm; reuse region for a_T
  float* out = (float*)d_out;

  prep_weights<<<dim3(2048), dim3(256), 0, stream>>>(qw, kw, vw, pw, w2qkv, w2p);
  bn_prep<<<dim3(8), dim3(256), 0, stream>>>(
      (const float*)d_in[2], (const float*)d_in[3], (const float*)d_in[4], (const float*)d_in[5],
      (const float*)d_in[7], (const float*)d_in[8], (const float*)d_in[9], (const float*)d_in[10],
      (const float*)d_in[12], (const float*)d_in[13], (const float*)d_in[14], (const float*)d_in[15],
      (const float*)d_in[17], (const float*)d_in[18], (const float*)d_in[19], (const float*)d_in[20],
      inv4, add4);
  lif0<<<dim3(16, 8, 8), dim3(256), 0, stream>>>(x, sT);
  qkv_gemm<<<dim3(512), dim3(512), 0, stream>>>(w2qkv, sT, inv4, add4, qs, ks, vs);
  kv_gemm<<<dim3(256), dim3(256), 0, stream>>>(ks, vs, kvp);
  att_lif<<<dim3(8, 64), dim3(256), 0, stream>>>(qs, kvp, aT);
  proj_gemm<<<dim3(4, 8, 32), dim3(256), 0, stream>>>(w2p, aT, inv4, add4, pb, out);
}

// Round 11
// 277.314 us; speedup vs baseline: 1.1056x; 1.1056x over previous
//
#include <hip/hip_runtime.h>
#include <cstdint>
#include <cstddef>

typedef unsigned short u16;
typedef unsigned char u8;
typedef __attribute__((ext_vector_type(8))) short sh8;       // 8 x 16-bit (4 VGPR)
typedef __attribute__((ext_vector_type(8))) _Float16 hf8;    // 8 fp16 (4 VGPR)
typedef __attribute__((ext_vector_type(4))) float f4;        // 4 f32
typedef __attribute__((ext_vector_type(4))) int i4;          // 4 i32 (16B)

#define MFMA16B(a, b, c) __builtin_amdgcn_mfma_f32_16x16x32_bf16((a), (b), (c), 0, 0, 0)
#define MFMA16H(a, b, c) __builtin_amdgcn_mfma_f32_16x16x32_f16((a), (b), (c), 0, 0, 0)
#define MFMAI8(a, b, c)  __builtin_amdgcn_mfma_i32_16x16x64_i8((a), (b), (c), 0, 0, 0)

__device__ __forceinline__ u16 f2bf(float f) {
  union { float f; uint32_t u; } v; v.f = f;
  uint32_t u = v.u;
  uint32_t lsb = (u >> 16) & 1u;
  return (u16)((u + 0x7fffu + lsb) >> 16);   // RNE
}
__device__ __forceinline__ float bf2f(u16 h) {
  union { uint32_t u; float f; } v; v.u = ((uint32_t)h) << 16;
  return v.f;
}

// async global->LDS, 16B per lane. LDS dest must be linear in lane order.
__device__ __forceinline__ void aload16(const void* g, void* l) {
  __builtin_amdgcn_global_load_lds(
      (const __attribute__((address_space(1))) uint32_t*)g,
      (__attribute__((address_space(3))) uint32_t*)l, 16, 0, 0);
}

// 12 MFMAs: 6 m-frags x 2 n-frags into acc[mf][NB+nf]
#define MFMA12(Af, Bf, NB)                                                    \
  {                                                                           \
    __builtin_amdgcn_s_setprio(1);                                            \
    _Pragma("unroll") for (int nf = 0; nf < 2; ++nf)                          \
      _Pragma("unroll") for (int mf = 0; mf < 6; ++mf)                        \
        acc[mf][(NB) + nf] = MFMA16H(Af[mf], Bf[nf], acc[mf][(NB) + nf]);     \
    __builtin_amdgcn_s_setprio(0);                                            \
  }

// ---------------------------------------------------------------------------
// Kernel 1: split fp32 weights into 2 fp16 planes.
// qkv layout: [1536][1024] rows = (q|k|v), cols 0-511 = h0, 512-1023 = h1.
// proj layout: [sp][512][512].
// ---------------------------------------------------------------------------
__global__ void prep_weights(const float* __restrict__ qw, const float* __restrict__ kw,
                             const float* __restrict__ vw, const float* __restrict__ pw,
                             u16* __restrict__ w2qkv, u16* __restrict__ w2p) {
  #pragma clang fp contract(off)
  int row = blockIdx.x;  // 0..2047
  for (int c = threadIdx.x; c < 512; c += 256) {
    const float* src;
    if (row < 1536) {
      int br = row >> 9;
      src = (br == 0 ? qw : (br == 1 ? kw : vw)) + (size_t)(row & 511) * 512;
    } else {
      src = pw + (size_t)(row - 1536) * 512;
    }
    float w = src[c];
    _Float16 h0 = (_Float16)w;
    float r1 = w - (float)h0;
    _Float16 h1 = (_Float16)r1;
    union { _Float16 h; u16 u; } u0, u1;
    u0.h = h0; u1.h = h1;
    if (row < 1536) {
      w2qkv[(size_t)row * 1024 + c] = u0.u;
      w2qkv[(size_t)row * 1024 + 512 + c] = u1.u;
    } else {
      int m = row - 1536;
      w2p[(size_t)m * 512 + c] = u0.u;
      w2p[(size_t)(512 + m) * 512 + c] = u1.u;
    }
  }
}

// single launch: grid(8) = 4 sets x 2 halves
__global__ void bn_prep(const float* __restrict__ g0, const float* __restrict__ b0,
                        const float* __restrict__ m0, const float* __restrict__ v0,
                        const float* __restrict__ g1, const float* __restrict__ b1,
                        const float* __restrict__ m1, const float* __restrict__ v1,
                        const float* __restrict__ g2, const float* __restrict__ b2,
                        const float* __restrict__ m2, const float* __restrict__ v2,
                        const float* __restrict__ g3, const float* __restrict__ b3,
                        const float* __restrict__ m3, const float* __restrict__ v3,
                        float* __restrict__ inv, float* __restrict__ add) {
  #pragma clang fp contract(off)
  int s = blockIdx.x >> 1;
  int i = (blockIdx.x & 1) * 256 + threadIdx.x;
  const float* g  = s == 0 ? g0 : s == 1 ? g1 : s == 2 ? g2 : g3;
  const float* be = s == 0 ? b0 : s == 1 ? b1 : s == 2 ? b2 : b3;
  const float* mu = s == 0 ? m0 : s == 1 ? m1 : s == 2 ? m2 : m3;
  const float* va = s == 0 ? v0 : s == 1 ? v1 : s == 2 ? v2 : v3;
  float iv = g[i] / sqrtf(va[i] + 1e-5f);
  inv[s * 512 + i] = iv;
  add[s * 512 + i] = be[i] - mu[i] * iv;
}

// ---------------------------------------------------------------------------
// Kernel 2: LIF over x -> spikes, stored TRANSPOSED sT[t][b][n][c] (fp16: 0x3C00).
// ---------------------------------------------------------------------------
__global__ __launch_bounds__(256) void lif0(const float* __restrict__ x, u16* __restrict__ sT) {
  #pragma clang fp contract(off)
  __shared__ u16 st[64 * 80];   // [n][c] padded
  const int tid = threadIdx.x;
  const int n0 = blockIdx.x * 64;
  const int c0 = blockIdx.y * 64;
  const int b = blockIdx.z;
  const int cl = tid >> 2;
  const int ns = (tid & 3) * 16;
  const int nr = tid >> 2;
  const int cs = (tid & 3) * 16;
  float vv[16];
#pragma unroll
  for (int i = 0; i < 16; i++) vv[i] = 0.f;
  for (int t = 0; t < 4; ++t) {
    const float* xp = x + ((size_t)((t * 8 + b) * 512 + c0 + cl)) * 1024 + n0 + ns;
#pragma unroll
    for (int q = 0; q < 4; ++q) {
      f4 xv = *(const f4*)(xp + q * 4);
#pragma unroll
      for (int j = 0; j < 4; ++j) {
        int i = q * 4 + j;
        float v2 = vv[i] + (xv[j] - vv[i]) * 0.5f;   // v + (x-v)/tau
        int spk = (v2 - 1.0f >= 0.0f);
        st[(ns + i) * 80 + cl] = spk ? (u16)0x3C00 : (u16)0;   // fp16 one
        vv[i] = spk ? 0.0f : v2;
      }
    }
    __syncthreads();
    u16* gp = sT + ((size_t)((t * 8 + b) * 1024 + n0 + nr)) * 512 + c0 + cs;
    *(sh8*)(gp) = *(const sh8*)&st[nr * 80 + cs];
    *(sh8*)(gp + 8) = *(const sh8*)&st[nr * 80 + cs + 8];
    __syncthreads();
  }
}

// ---------------------------------------------------------------------------
// Kernel 3: stacked QKV GEMM + BN + LIF. BM=192 BN=256, 512 thr (2Mx4N waves).
// R6 structure (best measured): plane-shared pair-staged B (tri-buf),
// dbuf A, 4-phase barriers, counted vmcnt. q spikes -> bf16; k/v -> i8.
// ---------------------------------------------------------------------------
__global__ __launch_bounds__(512, 2) void qkv_gemm(
    const u16* __restrict__ w2,      // [1536][1024]  (h0 | h1)
    const u16* __restrict__ sT,      // [t][b][n][512]
    const float* __restrict__ inv4, const float* __restrict__ add4,
    u16* __restrict__ qs, u8* __restrict__ ks8, u8* __restrict__ vs8) {
  #pragma clang fp contract(off)
  __shared__ u16 lA[2][192 * 64];   // 2 x 24KB : [row][pl*32 + k]
  __shared__ u16 lB[3][256 * 64];   // 3 x 32KB : [row][sub*32 + k]
  const int tid = threadIdx.x;
  const int bid = blockIdx.x;               // 256 blocks
  const int orig = (bid & 7) * 32 + (bid >> 3);   // XCD-chunked (256%8==0)
  const int mI = orig & 7;
  const int nI = (orig >> 3) & 3;
  const int b  = orig >> 5;
  const int m0 = mI * 192;
  const int n0 = nI * 256;
  const int wid = tid >> 6, lane = tid & 63;
  const int l15 = lane & 15, l4 = lane >> 4;
  const int wm = wid >> 2, wn = wid & 3;    // 2M x 4N
  const int swz = l15 & 7;                  // read-side XOR
  const int srow = tid >> 3;
  const int ss = (tid & 7) ^ (srow & 7);
  int aoff[3];
#pragma unroll
  for (int c = 0; c < 3; ++c)
    aoff[c] = (m0 + c * 64 + srow) * 1024 + (ss >> 2) * 512 + (ss & 3) * 8;
  int boff[4];
#pragma unroll
  for (int c = 0; c < 4; ++c)
    boff[c] = (n0 + c * 64 + srow) * 512 + (ss >> 2) * 32 + (ss & 3) * 8;

  auto stA = [&](int ii) {                   // tile ii -> lA[ii&1]
    int k0 = (ii & 15) * 32;
    u16* d = &lA[ii & 1][0];
#pragma unroll
    for (int c = 0; c < 3; ++c)
      aload16(w2 + (size_t)(aoff[c] + k0), d + c * 4096 + tid * 8);
  };
  auto stB = [&](int P) {                    // pair P -> lB[P%3]
    int k0 = (P & 7) * 64;
    const u16* bb = sT + (size_t)(P >> 3) * 4194304 + (size_t)b * 524288;
    u16* d = &lB[P % 3][0];
#pragma unroll
    for (int c = 0; c < 4; ++c)
      aload16(bb + (size_t)(boff[c] + k0), d + c * 4096 + tid * 8);
  };

  const f4 fz = {0.f, 0.f, 0.f, 0.f};
  f4 acc[6][4];
  f4 vst[6][4];
#pragma unroll
  for (int i = 0; i < 6; i++)
#pragma unroll
    for (int j = 0; j < 4; j++) vst[i][j] = fz;

  // prologue: A(0), B(pair0), B(pair1)
  stA(0); stB(0); stB(1);
  asm volatile("s_waitcnt vmcnt(4)" ::: "memory");   // A(0)+B(0) done; B(1) flies
  __builtin_amdgcn_s_barrier();
  __builtin_amdgcn_sched_barrier(0);

  for (int t = 0; t < 4; ++t) {
#pragma unroll
    for (int i = 0; i < 6; i++)
#pragma unroll
      for (int j = 0; j < 4; j++) acc[i][j] = fz;

    for (int i = 0; i < 16; ++i) {
      const int ii = t * 16 + i;
      const int P = ii >> 1;
      const u16* bufA = &lA[ii & 1][0];
      const u16* bufB = &lB[P % 3][0];
      const int sb = (ii & 1) * 4;           // B slot base for this subtile
      const bool issueB = ((ii & 1) == 0) && (P + 2 < 32);
      // ---- phase 0: A-h0 frags + B nf0,1; issue prefetches
      hf8 A0[6], Bq[2];
#pragma unroll
      for (int mf = 0; mf < 6; ++mf) {
        int r = wm * 96 + mf * 16 + l15;
        A0[mf] = *(const hf8*)&bufA[r * 64 + ((l4 ^ swz) * 8)];
      }
#pragma unroll
      for (int nf = 0; nf < 2; ++nf) {
        int r = wn * 64 + nf * 16 + l15;
        Bq[nf] = *(const hf8*)&bufB[r * 64 + (((sb + l4) ^ swz) * 8)];
      }
      if (ii < 63) stA(ii + 1);
      if (issueB) stB(P + 2);
      __builtin_amdgcn_sched_barrier(0);
      __builtin_amdgcn_s_barrier();
      __builtin_amdgcn_sched_barrier(0);
      MFMA12(A0, Bq, 0);
      // ---- phase 1: B nf2,3
      hf8 B1[2];
#pragma unroll
      for (int nf = 0; nf < 2; ++nf) {
        int r = wn * 64 + (2 + nf) * 16 + l15;
        B1[nf] = *(const hf8*)&bufB[r * 64 + (((sb + l4) ^ swz) * 8)];
      }
      __builtin_amdgcn_sched_barrier(0);
      __builtin_amdgcn_s_barrier();
      __builtin_amdgcn_sched_barrier(0);
      MFMA12(A0, B1, 2);
      // ---- phase 2: A-h1 frags
      hf8 A1[6];
#pragma unroll
      for (int mf = 0; mf < 6; ++mf) {
        int r = wm * 96 + mf * 16 + l15;
        A1[mf] = *(const hf8*)&bufA[r * 64 + (((4 + l4) ^ swz) * 8)];
      }
      __builtin_amdgcn_sched_barrier(0);
      __builtin_amdgcn_s_barrier();
      __builtin_amdgcn_sched_barrier(0);
      MFMA12(A1, B1, 2);
      // ---- phase 3: B nf0,1 re-read
#pragma unroll
      for (int nf = 0; nf < 2; ++nf) {
        int r = wn * 64 + nf * 16 + l15;
        Bq[nf] = *(const hf8*)&bufB[r * 64 + (((sb + l4) ^ swz) * 8)];
      }
      __builtin_amdgcn_sched_barrier(0);
      __builtin_amdgcn_s_barrier();
      __builtin_amdgcn_sched_barrier(0);
      MFMA12(A1, Bq, 0);
      // ---- boundary: even keeps pair-ahead B in flight; odd drains all
      if (((ii & 1) == 0) && issueB) {
        asm volatile("s_waitcnt vmcnt(4)" ::: "memory");
      } else {
        asm volatile("s_waitcnt vmcnt(0)" ::: "memory");
      }
      __builtin_amdgcn_s_barrier();
      __builtin_amdgcn_sched_barrier(0);
    }
    // epilogue: BN + LIF + spike store (q: bf16; k/v: i8 for the i8 kv_gemm)
#pragma unroll
    for (int mf = 0; mf < 6; ++mf) {
      int f0 = m0 + wm * 96 + mf * 16;       // 16-aligned; never crosses 512
      int br = f0 >> 9;
      int ocb = f0 & 511;
#pragma unroll
      for (int r = 0; r < 4; ++r) {
        int oc = ocb + l4 * 4 + r;
        float iv = inv4[br * 512 + oc];
        float ad = add4[br * 512 + oc];
        size_t rowbase = ((size_t)((t * 8 + b) * 512 + oc)) * 1024 + n0;
#pragma unroll
        for (int nf = 0; nf < 4; ++nf) {
          float z = acc[mf][nf][r] * iv + ad;
          float v2 = vst[mf][nf][r];
          v2 = v2 + (z - v2) * 0.5f;
          int spk = (v2 - 1.0f >= 0.0f);
          vst[mf][nf][r] = spk ? 0.0f : v2;
          size_t idx = rowbase + wn * 64 + nf * 16 + l15;
          if (br == 0) {
            qs[idx] = spk ? (u16)0x3F80 : (u16)0;       // bf16 one
          } else {
            u8* d8 = (br == 1) ? ks8 : vs8;
            d8[idx] = (u8)spk;                          // i8 one
          }
        }
      }
    }
  }
}

// ---------------------------------------------------------------------------
// Kernel 4: kvT[e][d] = sum_n v[e,n]*k[d,n], per (t,b,h), K=1024 in i8 MFMA.
// Integer-exact (sums <= 1024); kvp bits identical to the fp32-MFMA version.
// ---------------------------------------------------------------------------
__global__ __launch_bounds__(256) void kv_gemm(const u8* __restrict__ ks8,
                                               const u8* __restrict__ vs8,
                                               float* __restrict__ kvp) {
  const int tbh = blockIdx.x;  // (t*8+b)*8+h ; 256 blocks
  const int tid = threadIdx.x;
  const int wv = tid >> 6, lane = tid & 63, l15 = lane & 15, l4 = lane >> 4;
  const size_t cb = ((size_t)(tbh >> 3) * 512 + (size_t)(tbh & 7) * 64) * 1024;
  const u8* vbase = vs8 + cb;
  const u8* kbase = ks8 + cb;
  const i4 iz = {0, 0, 0, 0};
  i4 acc[4];
#pragma unroll
  for (int i = 0; i < 4; i++) acc[i] = iz;
  for (int s = 0; s < 16; ++s) {             // K=1024, 64 per MFMA
    int kk = s * 64 + l4 * 16;
    i4 av = *(const i4*)(vbase + (size_t)(wv * 16 + l15) * 1024 + kk);
#pragma unroll
    for (int df = 0; df < 4; ++df) {
      i4 bk = *(const i4*)(kbase + (size_t)(df * 16 + l15) * 1024 + kk);
      acc[df] = MFMAI8(av, bk, acc[df]);
    }
  }
  float* out = kvp + (size_t)tbh * 4096;
#pragma unroll
  for (int df = 0; df < 4; ++df)
#pragma unroll
    for (int r = 0; r < 4; ++r)
      out[(wv * 16 + l4 * 4 + r) * 64 + df * 16 + l15] = (float)acc[df][r];
}

// ---------------------------------------------------------------------------
// Kernel 5: att = (kv^T @ q)*0.125 per head, then LIF; exact integer path.
// ---------------------------------------------------------------------------
__global__ __launch_bounds__(256) void att_lif(const u16* __restrict__ qs,
                                               const float* __restrict__ kvp,
                                               u16* __restrict__ aT) {
  #pragma clang fp contract(off)
  __shared__ u16 ldsb[64 * 72 * 2 + 128 * 72];
  u16* lkhi = ldsb;                 // [64 e][72]
  u16* lklo = ldsb + 64 * 72;       // [64 e][72]
  u16* lqT = ldsb + 64 * 72 * 2;    // [128 n][72]
  u16* lsp = ldsb;                  // alias: [128 n][72] spike transpose buf
  const int tid = threadIdx.x;
  const int n0 = blockIdx.x * 128;
  const int b = blockIdx.y >> 3;
  const int h = blockIdx.y & 7;
  const int wv = tid >> 6, lane = tid & 63, l15 = lane & 15, l4 = lane >> 4;
  const int e_s = tid >> 2, ds_ = (tid & 3) * 16;
  const f4 fz = {0.f, 0.f, 0.f, 0.f};
  f4 vst[4][2];
#pragma unroll
  for (int i = 0; i < 4; i++)
#pragma unroll
    for (int j = 0; j < 2; j++) vst[i][j] = fz;

  for (int t = 0; t < 4; ++t) {
    int tb = t * 8 + b;
    int tbh = tb * 8 + h;
    {  // stage kv: split into exact bf16 hi/lo
      const float* base = kvp + (size_t)tbh * 4096 + e_s * 64 + ds_;
#pragma unroll
      for (int q = 0; q < 4; ++q) {
        f4 s4 = *(const f4*)(base + q * 4);
#pragma unroll
        for (int j = 0; j < 4; ++j) {
          float sv = s4[j];
          u16 hb = f2bf(sv);
          float lof = sv - bf2f(hb);
          lkhi[e_s * 72 + ds_ + q * 4 + j] = hb;
          lklo[e_s * 72 + ds_ + q * 4 + j] = f2bf(lof);
        }
      }
    }
    {  // stage q transposed: lqT[n][d]
      const u16* qb = qs + ((size_t)tb * 512 + h * 64) * 1024 + n0;
#pragma unroll
      for (int it = 0; it < 4; ++it) {
        int lin = it * 2048 + tid * 8;
        int d = lin >> 7, j0 = lin & 127;
        sh8 qv = *(const sh8*)(qb + (size_t)d * 1024 + j0);
#pragma unroll
        for (int j = 0; j < 8; ++j) lqT[(j0 + j) * 72 + d] = (u16)qv[j];
      }
    }
    __syncthreads();
    f4 acc[4][2];
#pragma unroll
    for (int i = 0; i < 4; i++)
#pragma unroll
      for (int j = 0; j < 2; j++) acc[i][j] = fz;
#pragma unroll
    for (int ksx = 0; ksx < 2; ++ksx) {
      sh8 bq[2];
#pragma unroll
      for (int nf = 0; nf < 2; ++nf)
        bq[nf] = *(const sh8*)&lqT[(wv * 32 + nf * 16 + l15) * 72 + ksx * 32 + l4 * 8];
#pragma unroll
      for (int mf = 0; mf < 4; ++mf) {
        sh8 ah = *(const sh8*)&lkhi[(mf * 16 + l15) * 72 + ksx * 32 + l4 * 8];
        sh8 al = *(const sh8*)&lklo[(mf * 16 + l15) * 72 + ksx * 32 + l4 * 8];
#pragma unroll
        for (int nf = 0; nf < 2; ++nf) {
          acc[mf][nf] = MFMA16B(ah, bq[nf], acc[mf][nf]);
          acc[mf][nf] = MFMA16B(al, bq[nf], acc[mf][nf]);
        }
      }
    }
    __syncthreads();  // all reads of lkhi/lklo done before alias overwrite
#pragma unroll
    for (int mf = 0; mf < 4; ++mf)
#pragma unroll
      for (int nf = 0; nf < 2; ++nf)
#pragma unroll
        for (int r = 0; r < 4; ++r) {
          float xatt = acc[mf][nf][r] * 0.125f;  // exact
          float v2 = vst[mf][nf][r];
          v2 = v2 + (xatt - v2) * 0.5f;          // exact dyadic
          int spk = (v2 - 1.0f >= 0.0f);
          vst[mf][nf][r] = spk ? 0.0f : v2;
          int e = mf * 16 + l4 * 4 + r;
          int n = wv * 32 + nf * 16 + l15;
          lsp[n * 72 + e] = spk ? (u16)0x3C00 : (u16)0;   // fp16 one
        }
    __syncthreads();
    {  // store a_T rows (c contiguous)
#pragma unroll
      for (int it = 0; it < 2; ++it) {
        int lin = it * 256 + tid;
        int n = lin >> 2, es = (lin & 3) * 16;
        u16* gp = aT + ((size_t)(tb * 1024 + n0 + n)) * 512 + h * 64 + es;
        *(sh8*)gp = *(const sh8*)&lsp[n * 72 + es];
        *(sh8*)(gp + 8) = *(const sh8*)&lsp[n * 72 + es + 8];
      }
    }
    __syncthreads();
  }
}

// ---------------------------------------------------------------------------
// Kernel 6: proj GEMM (2-plane fp16) + bias + BN -> out fp32 (R6 structure).
// ---------------------------------------------------------------------------
__global__ __launch_bounds__(256, 2) void proj_gemm(
    const u16* __restrict__ w2, const u16* __restrict__ aT,
    const float* __restrict__ inv4, const float* __restrict__ add4,
    const float* __restrict__ pb, float* __restrict__ out) {
  #pragma clang fp contract(off)
  __shared__ u16 lA[2 * 128 * 32];
  __shared__ u16 lB[128 * 32];
  const int tid = threadIdx.x;
  const int m0 = blockIdx.x * 128;
  const int n0 = blockIdx.y * 128;
  const int tb = blockIdx.z;
  const int lane = tid & 63, wv = tid >> 6;
  const int l15 = lane & 15, l4 = lane >> 4;
  const int wm = wv >> 1, wn = wv & 1;
  const int rA = tid >> 2;
  const int kswz = (((tid & 3) ^ ((tid >> 3) & 3)) * 8);
  const int sA = (l4 ^ ((l15 >> 1) & 3)) * 8;

  size_t aoff[4];
#pragma unroll
  for (int c = 0; c < 4; ++c) {
    int rf = c * 64 + rA;
    int sp = rf >> 7, r = rf & 127;
    aoff[c] = (size_t)(sp * 512 + m0 + r) * 512 + kswz;
  }
  size_t boff[2];
#pragma unroll
  for (int c = 0; c < 2; ++c) boff[c] = (size_t)(c * 64 + rA) * 512 + kswz;

  const f4 fz = {0.f, 0.f, 0.f, 0.f};
  f4 acc[4][4];
#pragma unroll
  for (int i = 0; i < 4; i++)
#pragma unroll
    for (int j = 0; j < 4; j++) acc[i][j] = fz;
  const u16* aTt = aT + ((size_t)tb * 1024 + n0) * 512;

  for (int k0 = 0; k0 < 512; k0 += 32) {
#pragma unroll
    for (int c = 0; c < 4; ++c)
      aload16(w2 + aoff[c] + k0, &lA[c * 2048 + tid * 8]);
#pragma unroll
    for (int c = 0; c < 2; ++c)
      aload16(aTt + boff[c] + k0, &lB[c * 2048 + tid * 8]);
    __syncthreads();
    hf8 bfr[4];
#pragma unroll
    for (int nf = 0; nf < 4; ++nf)
      bfr[nf] = *(const hf8*)&lB[(wn * 64 + nf * 16 + l15) * 32 + sA];
#pragma unroll
    for (int sp = 0; sp < 2; ++sp) {
#pragma unroll
      for (int mf = 0; mf < 4; ++mf) {
        hf8 afr = *(const hf8*)&lA[sp * 4096 + (wm * 64 + mf * 16 + l15) * 32 + sA];
#pragma unroll
        for (int nf = 0; nf < 4; ++nf) acc[mf][nf] = MFMA16H(afr, bfr[nf], acc[mf][nf]);
      }
    }
    __syncthreads();
  }
#pragma unroll
  for (int mf = 0; mf < 4; ++mf) {
#pragma unroll
    for (int r = 0; r < 4; ++r) {
      int o = m0 + wm * 64 + mf * 16 + l4 * 4 + r;
      float iv = inv4[3 * 512 + o];
      float ad = add4[3 * 512 + o];
      float bias = pb[o];
      size_t rowbase = ((size_t)(tb * 512 + o)) * 1024 + n0;
#pragma unroll
      for (int nf = 0; nf < 4; ++nf) {
        float z = (acc[mf][nf][r] + bias) * iv + ad;
        out[rowbase + wn * 64 + nf * 16 + l15] = z;
      }
    }
  }
}

// ---------------------------------------------------------------------------
extern "C" void kernel_launch(void* const* d_in, const int* in_sizes, int n_in,
                              void* d_out, int out_size, void* d_ws, size_t ws_size,
                              hipStream_t stream) {
  const float* x = (const float*)d_in[0];
  const float* qw = (const float*)d_in[1];
  const float* kw = (const float*)d_in[6];
  const float* vw = (const float*)d_in[11];
  const float* pw = (const float*)d_in[16];
  const float* pb = (const float*)d_in[21];

  char* p = (char*)d_ws;
  u16* w2qkv = (u16*)p; p += (size_t)1536 * 1024 * 2;      // 3.1 MB
  u16* w2p = (u16*)p;   p += (size_t)2 * 512 * 512 * 2;    // 1.0 MB
  float* inv4 = (float*)p; p += 4 * 512 * 4;
  float* add4 = (float*)p; p += 4 * 512 * 4;
  u16* sT = (u16*)p;    p += (size_t)4 * 8 * 1024 * 512 * 2;  // 33.5 MB (reused as aT)
  u16* qs = (u16*)p;    p += (size_t)4 * 8 * 512 * 1024 * 2;  // 33.5 MB bf16
  u8* ks8 = (u8*)p;     p += (size_t)4 * 8 * 512 * 1024;      // 16.8 MB i8
  u8* vs8 = (u8*)p;     p += (size_t)4 * 8 * 512 * 1024;      // 16.8 MB i8
  float* kvp = (float*)p; p += (size_t)256 * 4096 * 4;        // 4.2 MB
  u16* aT = sT;  // s_T dead after qkv_gemm; reuse region for a_T
  float* out = (float*)d_out;

  prep_weights<<<dim3(2048), dim3(256), 0, stream>>>(qw, kw, vw, pw, w2qkv, w2p);
  bn_prep<<<dim3(8), dim3(256), 0, stream>>>(
      (const float*)d_in[2], (const float*)d_in[3], (const float*)d_in[4], (const float*)d_in[5],
      (const float*)d_in[7], (const float*)d_in[8], (const float*)d_in[9], (const float*)d_in[10],
      (const float*)d_in[12], (const float*)d_in[13], (const float*)d_in[14], (const float*)d_in[15],
      (const float*)d_in[17], (const float*)d_in[18], (const float*)d_in[19], (const float*)d_in[20],
      inv4, add4);
  lif0<<<dim3(16, 8, 8), dim3(256), 0, stream>>>(x, sT);
  qkv_gemm<<<dim3(256), dim3(512), 0, stream>>>(w2qkv, sT, inv4, add4, qs, ks8, vs8);
  kv_gemm<<<dim3(256), dim3(256), 0, stream>>>(ks8, vs8, kvp);
  att_lif<<<dim3(8, 64), dim3(256), 0, stream>>>(qs, kvp, aT);
  proj_gemm<<<dim3(4, 8, 32), dim3(256), 0, stream>>>(w2p, aT, inv4, add4, pb, out);
}

// Round 12
// 241.095 us; speedup vs baseline: 1.2717x; 1.1502x over previous
//
#include <hip/hip_runtime.h>
#include <cstdint>
#include <cstddef>

typedef unsigned short u16;
typedef __attribute__((ext_vector_type(8))) short sh8;       // 8 x 16-bit (4 VGPR)
typedef __attribute__((ext_vector_type(8))) _Float16 hf8;    // 8 fp16 (4 VGPR)
typedef __attribute__((ext_vector_type(4))) float f4;        // 4 f32

#define MFMA16B(a, b, c) __builtin_amdgcn_mfma_f32_16x16x32_bf16((a), (b), (c), 0, 0, 0)
#define MFMA16H(a, b, c) __builtin_amdgcn_mfma_f32_16x16x32_f16((a), (b), (c), 0, 0, 0)

__device__ __forceinline__ u16 f2bf(float f) {
  union { float f; uint32_t u; } v; v.f = f;
  uint32_t u = v.u;
  uint32_t lsb = (u >> 16) & 1u;
  return (u16)((u + 0x7fffu + lsb) >> 16);   // RNE
}
__device__ __forceinline__ float bf2f(u16 h) {
  union { uint32_t u; float f; } v; v.u = ((uint32_t)h) << 16;
  return v.f;
}

// async global->LDS, 16B per lane. LDS dest must be linear in lane order.
__device__ __forceinline__ void aload16(const void* g, void* l) {
  __builtin_amdgcn_global_load_lds(
      (const __attribute__((address_space(1))) uint32_t*)g,
      (__attribute__((address_space(3))) uint32_t*)l, 16, 0, 0);
}

__device__ __forceinline__ void pbar() {            // phase barrier (no drain)
  __builtin_amdgcn_sched_barrier(0);
  __builtin_amdgcn_s_barrier();
  __builtin_amdgcn_sched_barrier(0);
}

// 12 MFMAs: 6 m-frags x 2 n-frags into acc[mf][NB+nf]
#define MFMA12(Af, Bf, NB)                                                    \
  {                                                                           \
    __builtin_amdgcn_s_setprio(1);                                            \
    _Pragma("unroll") for (int nf = 0; nf < 2; ++nf)                          \
      _Pragma("unroll") for (int mf = 0; mf < 6; ++mf)                        \
        acc[mf][(NB) + nf] = MFMA16H(Af[mf], Bf[nf], acc[mf][(NB) + nf]);     \
    __builtin_amdgcn_s_setprio(0);                                            \
  }

// ---------------------------------------------------------------------------
// Kernel 1: split fp32 weights into 2 fp16 planes.
// qkv layout: [1536][1024] rows = (q|k|v), cols 0-511 = h0, 512-1023 = h1.
// proj layout: [sp][512][512].
// ---------------------------------------------------------------------------
__global__ void prep_weights(const float* __restrict__ qw, const float* __restrict__ kw,
                             const float* __restrict__ vw, const float* __restrict__ pw,
                             u16* __restrict__ w2qkv, u16* __restrict__ w2p) {
  #pragma clang fp contract(off)
  int row = blockIdx.x;  // 0..2047
  for (int c = threadIdx.x; c < 512; c += 256) {
    const float* src;
    if (row < 1536) {
      int br = row >> 9;
      src = (br == 0 ? qw : (br == 1 ? kw : vw)) + (size_t)(row & 511) * 512;
    } else {
      src = pw + (size_t)(row - 1536) * 512;
    }
    float w = src[c];
    _Float16 h0 = (_Float16)w;
    float r1 = w - (float)h0;
    _Float16 h1 = (_Float16)r1;
    union { _Float16 h; u16 u; } u0, u1;
    u0.h = h0; u1.h = h1;
    if (row < 1536) {
      w2qkv[(size_t)row * 1024 + c] = u0.u;
      w2qkv[(size_t)row * 1024 + 512 + c] = u1.u;
    } else {
      int m = row - 1536;
      w2p[(size_t)m * 512 + c] = u0.u;
      w2p[(size_t)(512 + m) * 512 + c] = u1.u;
    }
  }
}

// single launch: grid(8) = 4 sets x 2 halves
__global__ void bn_prep(const float* __restrict__ g0, const float* __restrict__ b0,
                        const float* __restrict__ m0, const float* __restrict__ v0,
                        const float* __restrict__ g1, const float* __restrict__ b1,
                        const float* __restrict__ m1, const float* __restrict__ v1,
                        const float* __restrict__ g2, const float* __restrict__ b2,
                        const float* __restrict__ m2, const float* __restrict__ v2,
                        const float* __restrict__ g3, const float* __restrict__ b3,
                        const float* __restrict__ m3, const float* __restrict__ v3,
                        float* __restrict__ inv, float* __restrict__ add) {
  #pragma clang fp contract(off)
  int s = blockIdx.x >> 1;
  int i = (blockIdx.x & 1) * 256 + threadIdx.x;
  const float* g  = s == 0 ? g0 : s == 1 ? g1 : s == 2 ? g2 : g3;
  const float* be = s == 0 ? b0 : s == 1 ? b1 : s == 2 ? b2 : b3;
  const float* mu = s == 0 ? m0 : s == 1 ? m1 : s == 2 ? m2 : m3;
  const float* va = s == 0 ? v0 : s == 1 ? v1 : s == 2 ? v2 : v3;
  float iv = g[i] / sqrtf(va[i] + 1e-5f);
  inv[s * 512 + i] = iv;
  add[s * 512 + i] = be[i] - mu[i] * iv;
}

// ---------------------------------------------------------------------------
// Kernel 2: LIF over x -> spikes, stored TRANSPOSED sT[t][b][n][c] (fp16: 0x3C00).
// ---------------------------------------------------------------------------
__global__ __launch_bounds__(256) void lif0(const float* __restrict__ x, u16* __restrict__ sT) {
  #pragma clang fp contract(off)
  __shared__ u16 st[64 * 80];   // [n][c] padded
  const int tid = threadIdx.x;
  const int n0 = blockIdx.x * 64;
  const int c0 = blockIdx.y * 64;
  const int b = blockIdx.z;
  const int cl = tid >> 2;
  const int ns = (tid & 3) * 16;
  const int nr = tid >> 2;
  const int cs = (tid & 3) * 16;
  float vv[16];
#pragma unroll
  for (int i = 0; i < 16; i++) vv[i] = 0.f;
  for (int t = 0; t < 4; ++t) {
    const float* xp = x + ((size_t)((t * 8 + b) * 512 + c0 + cl)) * 1024 + n0 + ns;
#pragma unroll
    for (int q = 0; q < 4; ++q) {
      f4 xv = *(const f4*)(xp + q * 4);
#pragma unroll
      for (int j = 0; j < 4; ++j) {
        int i = q * 4 + j;
        float v2 = vv[i] + (xv[j] - vv[i]) * 0.5f;   // v + (x-v)/tau
        int spk = (v2 - 1.0f >= 0.0f);
        st[(ns + i) * 80 + cl] = spk ? (u16)0x3C00 : (u16)0;   // fp16 one
        vv[i] = spk ? 0.0f : v2;
      }
    }
    __syncthreads();
    u16* gp = sT + ((size_t)((t * 8 + b) * 1024 + n0 + nr)) * 512 + c0 + cs;
    *(sh8*)(gp) = *(const sh8*)&st[nr * 80 + cs];
    *(sh8*)(gp + 8) = *(const sh8*)&st[nr * 80 + cs + 8];
    __syncthreads();
  }
}

// ---------------------------------------------------------------------------
// Kernel 3: stacked QKV GEMM + BN + LIF. BM=192 BN=256, 512 thr (2Mx4N waves).
// R6 structure (measured optimum): plane-shared staging, A dbuf 2x24KB,
// B pair-staged tri-buf 3x32KB, 4-phase barriers, counted vmcnt(4)/(0).
// ---------------------------------------------------------------------------
__global__ __launch_bounds__(512, 2) void qkv_gemm(
    const u16* __restrict__ w2,      // [1536][1024]  (h0 | h1)
    const u16* __restrict__ sT,      // [t][b][n][512]
    const float* __restrict__ inv4, const float* __restrict__ add4,
    u16* __restrict__ qs, u16* __restrict__ ks, u16* __restrict__ vs) {
  #pragma clang fp contract(off)
  __shared__ u16 lA[2][192 * 64];   // 2 x 24KB : [row][pl*32 + k]
  __shared__ u16 lB[3][256 * 64];   // 3 x 32KB : [row][sub*32 + k]
  const int tid = threadIdx.x;
  const int bid = blockIdx.x;               // 256 blocks
  const int orig = (bid & 7) * 32 + (bid >> 3);   // XCD-chunked (256%8==0)
  const int mI = orig & 7;
  const int nI = (orig >> 3) & 3;
  const int b  = orig >> 5;
  const int m0 = mI * 192;
  const int n0 = nI * 256;
  const int wid = tid >> 6, lane = tid & 63;
  const int l15 = lane & 15, l4 = lane >> 4;
  const int wm = wid >> 2, wn = wid & 3;    // 2M x 4N
  const int swz = l15 & 7;                  // read-side XOR
  const int srow = tid >> 3;
  const int ss = (tid & 7) ^ (srow & 7);
  int aoff[3];
#pragma unroll
  for (int c = 0; c < 3; ++c)
    aoff[c] = (m0 + c * 64 + srow) * 1024 + (ss >> 2) * 512 + (ss & 3) * 8;
  int boff[4];
#pragma unroll
  for (int c = 0; c < 4; ++c)
    boff[c] = (n0 + c * 64 + srow) * 512 + (ss >> 2) * 32 + (ss & 3) * 8;

  auto stA = [&](int ii) {                   // tile ii -> lA[ii&1]
    int k0 = (ii & 15) * 32;
    u16* d = &lA[ii & 1][0];
#pragma unroll
    for (int c = 0; c < 3; ++c)
      aload16(w2 + (size_t)(aoff[c] + k0), d + c * 4096 + tid * 8);
  };
  auto stB = [&](int P) {                    // pair P -> lB[P%3]
    int k0 = (P & 7) * 64;
    const u16* bb = sT + (size_t)(P >> 3) * 4194304 + (size_t)b * 524288;
    u16* d = &lB[P % 3][0];
#pragma unroll
    for (int c = 0; c < 4; ++c)
      aload16(bb + (size_t)(boff[c] + k0), d + c * 4096 + tid * 8);
  };

  const f4 fz = {0.f, 0.f, 0.f, 0.f};
  f4 acc[6][4];
  f4 vst[6][4];
#pragma unroll
  for (int i = 0; i < 6; i++)
#pragma unroll
    for (int j = 0; j < 4; j++) vst[i][j] = fz;

  // prologue: A(0), B(pair0), B(pair1)
  stA(0); stB(0); stB(1);
  asm volatile("s_waitcnt vmcnt(4)" ::: "memory");   // A(0)+B(0) done; B(1) flies
  __builtin_amdgcn_s_barrier();
  __builtin_amdgcn_sched_barrier(0);

  for (int t = 0; t < 4; ++t) {
#pragma unroll
    for (int i = 0; i < 6; i++)
#pragma unroll
      for (int j = 0; j < 4; j++) acc[i][j] = fz;

    for (int i = 0; i < 16; ++i) {
      const int ii = t * 16 + i;
      const int P = ii >> 1;
      const u16* bufA = &lA[ii & 1][0];
      const u16* bufB = &lB[P % 3][0];
      const int sb = (ii & 1) * 4;           // B slot base for this subtile
      const bool issueB = ((ii & 1) == 0) && (P + 2 < 32);
      // ---- phase 0: A-h0 frags + B nf0,1; issue prefetches
      hf8 A0[6], Bq[2];
#pragma unroll
      for (int mf = 0; mf < 6; ++mf) {
        int r = wm * 96 + mf * 16 + l15;
        A0[mf] = *(const hf8*)&bufA[r * 64 + ((l4 ^ swz) * 8)];
      }
#pragma unroll
      for (int nf = 0; nf < 2; ++nf) {
        int r = wn * 64 + nf * 16 + l15;
        Bq[nf] = *(const hf8*)&bufB[r * 64 + (((sb + l4) ^ swz) * 8)];
      }
      if (ii < 63) stA(ii + 1);
      if (issueB) stB(P + 2);
      pbar();
      MFMA12(A0, Bq, 0);
      // ---- phase 1: B nf2,3
      hf8 B1[2];
#pragma unroll
      for (int nf = 0; nf < 2; ++nf) {
        int r = wn * 64 + (2 + nf) * 16 + l15;
        B1[nf] = *(const hf8*)&bufB[r * 64 + (((sb + l4) ^ swz) * 8)];
      }
      pbar();
      MFMA12(A0, B1, 2);
      // ---- phase 2: A-h1 frags
      hf8 A1[6];
#pragma unroll
      for (int mf = 0; mf < 6; ++mf) {
        int r = wm * 96 + mf * 16 + l15;
        A1[mf] = *(const hf8*)&bufA[r * 64 + (((4 + l4) ^ swz) * 8)];
      }
      pbar();
      MFMA12(A1, B1, 2);
      // ---- phase 3: B nf0,1 re-read
#pragma unroll
      for (int nf = 0; nf < 2; ++nf) {
        int r = wn * 64 + nf * 16 + l15;
        Bq[nf] = *(const hf8*)&bufB[r * 64 + (((sb + l4) ^ swz) * 8)];
      }
      pbar();
      MFMA12(A1, Bq, 0);
      // ---- boundary: even keeps pair-ahead B in flight; odd drains all
      if (((ii & 1) == 0) && issueB) {
        asm volatile("s_waitcnt vmcnt(4)" ::: "memory");
      } else {
        asm volatile("s_waitcnt vmcnt(0)" ::: "memory");
      }
      __builtin_amdgcn_s_barrier();
      __builtin_amdgcn_sched_barrier(0);
    }
    // epilogue: BN + LIF + spike store (bf16 spikes)
#pragma unroll
    for (int mf = 0; mf < 6; ++mf) {
      int f0 = m0 + wm * 96 + mf * 16;       // 16-aligned; never crosses 512
      int br = f0 >> 9;
      u16* dst = br == 0 ? qs : (br == 1 ? ks : vs);
      int ocb = f0 & 511;
#pragma unroll
      for (int r = 0; r < 4; ++r) {
        int oc = ocb + l4 * 4 + r;
        float iv = inv4[br * 512 + oc];
        float ad = add4[br * 512 + oc];
        size_t rowbase = ((size_t)((t * 8 + b) * 512 + oc)) * 1024 + n0;
#pragma unroll
        for (int nf = 0; nf < 4; ++nf) {
          float z = acc[mf][nf][r] * iv + ad;
          float v2 = vst[mf][nf][r];
          v2 = v2 + (z - v2) * 0.5f;
          int spk = (v2 - 1.0f >= 0.0f);
          vst[mf][nf][r] = spk ? 0.0f : v2;
          dst[rowbase + wn * 64 + nf * 16 + l15] = spk ? (u16)0x3F80 : (u16)0;
        }
      }
    }
  }
}

// ---------------------------------------------------------------------------
// Kernel 4: kvT[e][d] = sum_n v[e,n]*k[d,n], per (t,b,h), single pass K=1024.
// ---------------------------------------------------------------------------
__global__ __launch_bounds__(256) void kv_gemm(const u16* __restrict__ ks,
                                               const u16* __restrict__ vs,
                                               float* __restrict__ kvp) {
  const int tbh = blockIdx.x;  // (t*8+b)*8+h ; 256 blocks
  const int tid = threadIdx.x;
  const int wv = tid >> 6, lane = tid & 63, l15 = lane & 15, l4 = lane >> 4;
  const size_t cb = ((size_t)(tbh >> 3) * 512 + (size_t)(tbh & 7) * 64) * 1024;
  const u16* vbase = vs + cb;
  const u16* kbase = ks + cb;
  const f4 fz = {0.f, 0.f, 0.f, 0.f};
  f4 acc[4];
#pragma unroll
  for (int i = 0; i < 4; i++) acc[i] = fz;
  for (int s = 0; s < 32; ++s) {
    int kk = s * 32 + l4 * 8;
    sh8 av = *(const sh8*)(vbase + (size_t)(wv * 16 + l15) * 1024 + kk);
#pragma unroll
    for (int df = 0; df < 4; ++df) {
      sh8 bk = *(const sh8*)(kbase + (size_t)(df * 16 + l15) * 1024 + kk);
      acc[df] = MFMA16B(av, bk, acc[df]);
    }
  }
  float* out = kvp + (size_t)tbh * 4096;
#pragma unroll
  for (int df = 0; df < 4; ++df)
#pragma unroll
    for (int r = 0; r < 4; ++r)
      out[(wv * 16 + l4 * 4 + r) * 64 + df * 16 + l15] = acc[df][r];
}

// ---------------------------------------------------------------------------
// Kernel 5: att = (kv^T @ q)*0.125 per head, then LIF; exact integer path.
// ---------------------------------------------------------------------------
__global__ __launch_bounds__(256) void att_lif(const u16* __restrict__ qs,
                                               const float* __restrict__ kvp,
                                               u16* __restrict__ aT) {
  #pragma clang fp contract(off)
  __shared__ u16 ldsb[64 * 72 * 2 + 128 * 72];
  u16* lkhi = ldsb;                 // [64 e][72]
  u16* lklo = ldsb + 64 * 72;       // [64 e][72]
  u16* lqT = ldsb + 64 * 72 * 2;    // [128 n][72]
  u16* lsp = ldsb;                  // alias: [128 n][72] spike transpose buf
  const int tid = threadIdx.x;
  const int n0 = blockIdx.x * 128;
  const int b = blockIdx.y >> 3;
  const int h = blockIdx.y & 7;
  const int wv = tid >> 6, lane = tid & 63, l15 = lane & 15, l4 = lane >> 4;
  const int e_s = tid >> 2, ds_ = (tid & 3) * 16;
  const f4 fz = {0.f, 0.f, 0.f, 0.f};
  f4 vst[4][2];
#pragma unroll
  for (int i = 0; i < 4; i++)
#pragma unroll
    for (int j = 0; j < 2; j++) vst[i][j] = fz;

  for (int t = 0; t < 4; ++t) {
    int tb = t * 8 + b;
    int tbh = tb * 8 + h;
    {  // stage kv: split into exact bf16 hi/lo
      const float* base = kvp + (size_t)tbh * 4096 + e_s * 64 + ds_;
#pragma unroll
      for (int q = 0; q < 4; ++q) {
        f4 s4 = *(const f4*)(base + q * 4);
#pragma unroll
        for (int j = 0; j < 4; ++j) {
          float sv = s4[j];
          u16 hb = f2bf(sv);
          float lof = sv - bf2f(hb);
          lkhi[e_s * 72 + ds_ + q * 4 + j] = hb;
          lklo[e_s * 72 + ds_ + q * 4 + j] = f2bf(lof);
        }
      }
    }
    {  // stage q transposed: lqT[n][d]
      const u16* qb = qs + ((size_t)tb * 512 + h * 64) * 1024 + n0;
#pragma unroll
      for (int it = 0; it < 4; ++it) {
        int lin = it * 2048 + tid * 8;
        int d = lin >> 7, j0 = lin & 127;
        sh8 qv = *(const sh8*)(qb + (size_t)d * 1024 + j0);
#pragma unroll
        for (int j = 0; j < 8; ++j) lqT[(j0 + j) * 72 + d] = (u16)qv[j];
      }
    }
    __syncthreads();
    f4 acc[4][2];
#pragma unroll
    for (int i = 0; i < 4; i++)
#pragma unroll
      for (int j = 0; j < 2; j++) acc[i][j] = fz;
#pragma unroll
    for (int ksx = 0; ksx < 2; ++ksx) {
      sh8 bq[2];
#pragma unroll
      for (int nf = 0; nf < 2; ++nf)
        bq[nf] = *(const sh8*)&lqT[(wv * 32 + nf * 16 + l15) * 72 + ksx * 32 + l4 * 8];
#pragma unroll
      for (int mf = 0; mf < 4; ++mf) {
        sh8 ah = *(const sh8*)&lkhi[(mf * 16 + l15) * 72 + ksx * 32 + l4 * 8];
        sh8 al = *(const sh8*)&lklo[(mf * 16 + l15) * 72 + ksx * 32 + l4 * 8];
#pragma unroll
        for (int nf = 0; nf < 2; ++nf) {
          acc[mf][nf] = MFMA16B(ah, bq[nf], acc[mf][nf]);
          acc[mf][nf] = MFMA16B(al, bq[nf], acc[mf][nf]);
        }
      }
    }
    __syncthreads();  // all reads of lkhi/lklo done before alias overwrite
#pragma unroll
    for (int mf = 0; mf < 4; ++mf)
#pragma unroll
      for (int nf = 0; nf < 2; ++nf)
#pragma unroll
        for (int r = 0; r < 4; ++r) {
          float xatt = acc[mf][nf][r] * 0.125f;  // exact
          float v2 = vst[mf][nf][r];
          v2 = v2 + (xatt - v2) * 0.5f;          // exact dyadic
          int spk = (v2 - 1.0f >= 0.0f);
          vst[mf][nf][r] = spk ? 0.0f : v2;
          int e = mf * 16 + l4 * 4 + r;
          int n = wv * 32 + nf * 16 + l15;
          lsp[n * 72 + e] = spk ? (u16)0x3C00 : (u16)0;   // fp16 one
        }
    __syncthreads();
    {  // store a_T rows (c contiguous)
#pragma unroll
      for (int it = 0; it < 2; ++it) {
        int lin = it * 256 + tid;
        int n = lin >> 2, es = (lin & 3) * 16;
        u16* gp = aT + ((size_t)(tb * 1024 + n0 + n)) * 512 + h * 64 + es;
        *(sh8*)gp = *(const sh8*)&lsp[n * 72 + es];
        *(sh8*)(gp + 8) = *(const sh8*)&lsp[n * 72 + es + 8];
      }
    }
    __syncthreads();
  }
}

// ---------------------------------------------------------------------------
// Kernel 6: proj GEMM (2-plane fp16) + bias + BN -> out fp32 (R6 structure).
// ---------------------------------------------------------------------------
__global__ __launch_bounds__(256, 2) void proj_gemm(
    const u16* __restrict__ w2, const u16* __restrict__ aT,
    const float* __restrict__ inv4, const float* __restrict__ add4,
    const float* __restrict__ pb, float* __restrict__ out) {
  #pragma clang fp contract(off)
  __shared__ u16 lA[2 * 128 * 32];
  __shared__ u16 lB[128 * 32];
  const int tid = threadIdx.x;
  const int m0 = blockIdx.x * 128;
  const int n0 = blockIdx.y * 128;
  const int tb = blockIdx.z;
  const int lane = tid & 63, wv = tid >> 6;
  const int l15 = lane & 15, l4 = lane >> 4;
  const int wm = wv >> 1, wn = wv & 1;
  const int rA = tid >> 2;
  const int kswz = (((tid & 3) ^ ((tid >> 3) & 3)) * 8);
  const int sA = (l4 ^ ((l15 >> 1) & 3)) * 8;

  size_t aoff[4];
#pragma unroll
  for (int c = 0; c < 4; ++c) {
    int rf = c * 64 + rA;
    int sp = rf >> 7, r = rf & 127;
    aoff[c] = (size_t)(sp * 512 + m0 + r) * 512 + kswz;
  }
  size_t boff[2];
#pragma unroll
  for (int c = 0; c < 2; ++c) boff[c] = (size_t)(c * 64 + rA) * 512 + kswz;

  const f4 fz = {0.f, 0.f, 0.f, 0.f};
  f4 acc[4][4];
#pragma unroll
  for (int i = 0; i < 4; i++)
#pragma unroll
    for (int j = 0; j < 4; j++) acc[i][j] = fz;
  const u16* aTt = aT + ((size_t)tb * 1024 + n0) * 512;

  for (int k0 = 0; k0 < 512; k0 += 32) {
#pragma unroll
    for (int c = 0; c < 4; ++c)
      aload16(w2 + aoff[c] + k0, &lA[c * 2048 + tid * 8]);
#pragma unroll
    for (int c = 0; c < 2; ++c)
      aload16(aTt + boff[c] + k0, &lB[c * 2048 + tid * 8]);
    __syncthreads();
    hf8 bfr[4];
#pragma unroll
    for (int nf = 0; nf < 4; ++nf)
      bfr[nf] = *(const hf8*)&lB[(wn * 64 + nf * 16 + l15) * 32 + sA];
#pragma unroll
    for (int sp = 0; sp < 2; ++sp) {
#pragma unroll
      for (int mf = 0; mf < 4; ++mf) {
        hf8 afr = *(const hf8*)&lA[sp * 4096 + (wm * 64 + mf * 16 + l15) * 32 + sA];
#pragma unroll
        for (int nf = 0; nf < 4; ++nf) acc[mf][nf] = MFMA16H(afr, bfr[nf], acc[mf][nf]);
      }
    }
    __syncthreads();
  }
#pragma unroll
  for (int mf = 0; mf < 4; ++mf) {
#pragma unroll
    for (int r = 0; r < 4; ++r) {
      int o = m0 + wm * 64 + mf * 16 + l4 * 4 + r;
      float iv = inv4[3 * 512 + o];
      float ad = add4[3 * 512 + o];
      float bias = pb[o];
      size_t rowbase = ((size_t)(tb * 512 + o)) * 1024 + n0;
#pragma unroll
      for (int nf = 0; nf < 4; ++nf) {
        float z = (acc[mf][nf][r] + bias) * iv + ad;
        out[rowbase + wn * 64 + nf * 16 + l15] = z;
      }
    }
  }
}

// ---------------------------------------------------------------------------
extern "C" void kernel_launch(void* const* d_in, const int* in_sizes, int n_in,
                              void* d_out, int out_size, void* d_ws, size_t ws_size,
                              hipStream_t stream) {
  const float* x = (const float*)d_in[0];
  const float* qw = (const float*)d_in[1];
  const float* kw = (const float*)d_in[6];
  const float* vw = (const float*)d_in[11];
  const float* pw = (const float*)d_in[16];
  const float* pb = (const float*)d_in[21];

  char* p = (char*)d_ws;
  u16* w2qkv = (u16*)p; p += (size_t)1536 * 1024 * 2;      // 3.1 MB
  u16* w2p = (u16*)p;   p += (size_t)2 * 512 * 512 * 2;    // 1.0 MB
  float* inv4 = (float*)p; p += 4 * 512 * 4;
  float* add4 = (float*)p; p += 4 * 512 * 4;
  u16* sT = (u16*)p;    p += (size_t)4 * 8 * 1024 * 512 * 2;  // 33.5 MB (reused as aT)
  u16* qs = (u16*)p;    p += (size_t)4 * 8 * 512 * 1024 * 2;
  u16* ks = (u16*)p;    p += (size_t)4 * 8 * 512 * 1024 * 2;
  u16* vs = (u16*)p;    p += (size_t)4 * 8 * 512 * 1024 * 2;
  float* kvp = (float*)p; p += (size_t)256 * 4096 * 4;        // 4.2 MB
  u16* aT = sT;  // s_T dead after qkv_gemm; reuse region for a_T
  float* out = (float*)d_out;

  prep_weights<<<dim3(2048), dim3(256), 0, stream>>>(qw, kw, vw, pw, w2qkv, w2p);
  bn_prep<<<dim3(8), dim3(256), 0, stream>>>(
      (const float*)d_in[2], (const float*)d_in[3], (const float*)d_in[4], (const float*)d_in[5],
      (const float*)d_in[7], (const float*)d_in[8], (const float*)d_in[9], (const float*)d_in[10],
      (const float*)d_in[12], (const float*)d_in[13], (const float*)d_in[14], (const float*)d_in[15],
      (const float*)d_in[17], (const float*)d_in[18], (const float*)d_in[19], (const float*)d_in[20],
      inv4, add4);
  lif0<<<dim3(16, 8, 8), dim3(256), 0, stream>>>(x, sT);
  qkv_gemm<<<dim3(256), dim3(512), 0, stream>>>(w2qkv, sT, inv4, add4, qs, ks, vs);
  kv_gemm<<<dim3(256), dim3(256), 0, stream>>>(ks, vs, kvp);
  att_lif<<<dim3(8, 64), dim3(256), 0, stream>>>(qs, kvp, aT);
  proj_gemm<<<dim3(4, 8, 32), dim3(256), 0, stream>>>(w2p, aT, inv4, add4, pb, out);
}